// Round 1
// baseline (1942.286 us; speedup 1.0000x reference)
//
#include <hip/hip_runtime.h>
#include <cstddef>

#define Bn 4
#define Tn 2048
#define Cn 1024
#define Hn 16
#define Rn 256
#define Sn 64
#define Dn 64
static constexpr float SCALE = 0.125f; // 1/sqrt(64)

// ---------------------------------------------------------------------------
// Generic fp32 tiled GEMM: C = A[M,K] * op(B) (+bias)
//   BT=1: B is [N,K] row-major (use B[n*K+k])   -- all the *_proj weights
//   BT=0: B is [K,N] row-major (use B[k*N+n])   -- u_factor/v_factor [R,S]
// SMODE 0: C[m*N+n]
// SMODE 1: v-permute store: n -> (h=n>>6, d=n&63), m -> (b=m>>11, t=m&2047)
//          C[((b*16+h)*2048+t)*64+d]
// SMODE 2: per-head store (blockIdx.z = h, N==64):
//          C[((b*16+h)*2048+t)*64+n]
// 64x64 tile, BK=16, 256 threads, 4x4 micro-tile per thread.
// ---------------------------------------------------------------------------
template <int BT, int SMODE, int BIAS>
__global__ __launch_bounds__(256) void gemm_k(
    const float* __restrict__ A, const float* __restrict__ Bm,
    const float* __restrict__ bias, float* __restrict__ Cmat,
    int M, int N, int K, int bz_stride) {
  __shared__ float As[16][68];  // [k][m], padded for b128-aligned rows
  __shared__ float Bs[16][68];  // [k][n]

  const float* Bp = Bm + (size_t)blockIdx.z * bz_stride;
  const int tid = threadIdx.x;
  const int tx = tid & 15;        // 0..15
  const int ty = tid >> 4;        // 0..15
  const int m0 = blockIdx.x * 64;
  const int n0 = blockIdx.y * 64;

  float acc[4][4] = {};

  for (int k0 = 0; k0 < K; k0 += 16) {
    // stage A tile: 64 rows x 16 k; thread (ty=row-within-16, tx=k)
#pragma unroll
    for (int p = 0; p < 4; ++p) {
      int row = p * 16 + ty;
      As[tx][row] = A[(size_t)(m0 + row) * K + k0 + tx];
    }
    if (BT) {
#pragma unroll
      for (int p = 0; p < 4; ++p) {
        int row = p * 16 + ty;  // n index
        Bs[tx][row] = Bp[(size_t)(n0 + row) * K + k0 + tx];
      }
    } else {
      int n = tid & 63, kk = tid >> 6;  // 64 n x 4 k per pass
#pragma unroll
      for (int p = 0; p < 4; ++p) {
        Bs[kk + p * 4][n] = Bp[(size_t)(k0 + kk + p * 4) * N + n0 + n];
      }
    }
    __syncthreads();
#pragma unroll
    for (int kk = 0; kk < 16; ++kk) {
      float a[4], b[4];
#pragma unroll
      for (int i = 0; i < 4; ++i) a[i] = As[kk][ty * 4 + i];
#pragma unroll
      for (int j = 0; j < 4; ++j) b[j] = Bs[kk][tx * 4 + j];
#pragma unroll
      for (int i = 0; i < 4; ++i)
#pragma unroll
        for (int j = 0; j < 4; ++j) acc[i][j] += a[i] * b[j];
    }
    __syncthreads();
  }

  // epilogue
#pragma unroll
  for (int i = 0; i < 4; ++i) {
    int m = m0 + ty * 4 + i;
    int b = m >> 11, t = m & 2047;
#pragma unroll
    for (int j = 0; j < 4; ++j) {
      int n = n0 + tx * 4 + j;
      float val = acc[i][j];
      if (BIAS) val += bias[n];
      if (SMODE == 0) {
        Cmat[(size_t)m * N + n] = val;
      } else if (SMODE == 1) {
        int h = n >> 6, d = n & 63;
        Cmat[(((size_t)(b * Hn + h)) * Tn + t) * Dn + d] = val;
      } else {  // SMODE == 2
        Cmat[(((size_t)(b * Hn + (int)blockIdx.z)) * Tn + t) * Sn + n] = val;
      }
    }
  }
}

// ---------------------------------------------------------------------------
// Causal flash attention, fp32.
// grid = (T/256, B*H), block = 256. One thread per q-row.
// Q row (64f) and O accumulator (64f) live in registers; K/V tiles (64x64)
// staged in LDS; online softmax in chunks of 8 keys.
// q,k,v layout: [B*H][T][64]. Output written into y as [B,T,C] (col = h*64+d).
// ---------------------------------------------------------------------------
__global__ __launch_bounds__(256) void attn_k(
    const float* __restrict__ Q, const float* __restrict__ Kb,
    const float* __restrict__ Vb, float* __restrict__ Y) {
  __shared__ float Ks[64][64];
  __shared__ float Vs[64][64];

  const int tid = threadIdx.x;
  const int bh = blockIdx.y;
  const int tq = blockIdx.x * 256 + tid;
  const size_t base = (size_t)bh * Tn * 64;

  // Q row -> registers
  float4 qv[16];
  const float4* qp = (const float4*)(Q + base + (size_t)tq * 64);
#pragma unroll
  for (int i = 0; i < 16; ++i) qv[i] = qp[i];

  float4 o4[16];
#pragma unroll
  for (int i = 0; i < 16; ++i) o4[i] = make_float4(0.f, 0.f, 0.f, 0.f);
  float mx = -1e30f, l = 0.f;

  const int jmax = blockIdx.x * 4 + 3;  // highest key-tile any row here needs
  for (int j = 0; j <= jmax; ++j) {
    // stage K,V tile j (4096 floats each; 4 float4 per thread)
    {
      const float4* kp = (const float4*)(Kb + base + (size_t)j * 64 * 64);
      const float4* vp = (const float4*)(Vb + base + (size_t)j * 64 * 64);
      float4* ksp = (float4*)&Ks[0][0];
      float4* vsp = (float4*)&Vs[0][0];
#pragma unroll
      for (int p = 0; p < 4; ++p) {
        ksp[p * 256 + tid] = kp[p * 256 + tid];
        vsp[p * 256 + tid] = vp[p * 256 + tid];
      }
    }
    __syncthreads();

    const int kbase = j * 64;
    if (tq >= kbase) {
      const int ulim = min(63, tq - kbase);  // keys kbase+u <= tq
      for (int uc = 0; uc <= ulim; uc += 8) {
        float s[8];
#pragma unroll
        for (int i = 0; i < 8; ++i) s[i] = -1e30f;
        const int cnt = min(8, ulim - uc + 1);
        for (int i = 0; i < cnt; ++i) {
          const float4* kr = (const float4*)&Ks[uc + i][0];
          float a0 = 0.f, a1 = 0.f, a2 = 0.f, a3 = 0.f;
#pragma unroll
          for (int c = 0; c < 16; ++c) {
            float4 kv = kr[c];
            a0 += qv[c].x * kv.x;
            a1 += qv[c].y * kv.y;
            a2 += qv[c].z * kv.z;
            a3 += qv[c].w * kv.w;
          }
          s[i] = (a0 + a1 + a2 + a3) * SCALE;
        }
        // online softmax update for this chunk
        float cm = s[0];
#pragma unroll
        for (int i = 1; i < 8; ++i) cm = fmaxf(cm, s[i]);
        const float mnew = fmaxf(mx, cm);
        const float alpha = __expf(mx - mnew);
        float p[8];
        float ls = 0.f;
#pragma unroll
        for (int i = 0; i < 8; ++i) {
          p[i] = __expf(s[i] - mnew);  // masked lanes: exp(-huge)=0
          ls += p[i];
        }
        l = l * alpha + ls;
        mx = mnew;
#pragma unroll
        for (int d = 0; d < 16; ++d) {
          o4[d].x *= alpha; o4[d].y *= alpha; o4[d].z *= alpha; o4[d].w *= alpha;
        }
        for (int i = 0; i < cnt; ++i) {
          const float4* vr = (const float4*)&Vs[uc + i][0];
          const float pi = p[i];
#pragma unroll
          for (int d = 0; d < 16; ++d) {
            float4 vv = vr[d];
            o4[d].x += pi * vv.x;
            o4[d].y += pi * vv.y;
            o4[d].z += pi * vv.z;
            o4[d].w += pi * vv.w;
          }
        }
      }
    }
    __syncthreads();
  }

  // write y[b, tq, h*64 + d]
  const int b = bh >> 4, h = bh & 15;
  const float inv = 1.f / l;
  float4* yp = (float4*)(Y + ((size_t)(b * Tn + tq)) * Cn + h * 64);
#pragma unroll
  for (int d = 0; d < 16; ++d) {
    yp[d] = make_float4(o4[d].x * inv, o4[d].y * inv, o4[d].z * inv,
                        o4[d].w * inv);
  }
}

// ---------------------------------------------------------------------------
extern "C" void kernel_launch(void* const* d_in, const int* in_sizes, int n_in,
                              void* d_out, int out_size, void* d_ws,
                              size_t ws_size, hipStream_t stream) {
  const float* x        = (const float*)d_in[0];  // [B,T,C]
  const float* basis_w  = (const float*)d_in[1];  // [R,C]
  const float* u_factor = (const float*)d_in[2];  // [H,R,S]
  const float* v_factor = (const float*)d_in[3];  // [H,R,S]
  const float* v_proj_w = (const float*)d_in[4];  // [C,C]
  const float* v_proj_b = (const float*)d_in[5];  // [C]
  const float* o_proj_w = (const float*)d_in[6];  // [C,C]
  const float* o_proj_b = (const float*)d_in[7];  // [C]
  float* out = (float*)d_out;

  float* ws = (float*)d_ws;
  const size_t BT = (size_t)Bn * Tn;      // 8192
  const size_t BHTS = (size_t)Bn * Hn * Tn * 64;  // 8,388,608
  float* latent = ws;                     // [BT, R]
  float* qb = latent + BT * Rn;           // [B,H,T,S]
  float* kb = qb + BHTS;                  // [B,H,T,S]
  float* vb = kb + BHTS;                  // [B,H,T,D]
  float* yb = vb + BHTS;                  // [B,T,C]

  dim3 blk(256);
  // latent = x @ basis_w^T : [8192,256]
  gemm_k<1, 0, 0><<<dim3(128, 4, 1), blk, 0, stream>>>(
      x, basis_w, nullptr, latent, 8192, 256, 1024, 0);
  // q = latent @ u[h] : per-head [8192,64]
  gemm_k<0, 2, 0><<<dim3(128, 1, 16), blk, 0, stream>>>(
      latent, u_factor, nullptr, qb, 8192, 64, 256, Rn * Sn);
  // k = latent @ v[h]
  gemm_k<0, 2, 0><<<dim3(128, 1, 16), blk, 0, stream>>>(
      latent, v_factor, nullptr, kb, 8192, 64, 256, Rn * Sn);
  // v = x @ v_proj_w^T + b, stored permuted [B,H,T,D]
  gemm_k<1, 1, 1><<<dim3(128, 16, 1), blk, 0, stream>>>(
      x, v_proj_w, v_proj_b, vb, 8192, 1024, 1024, 0);
  // attention -> y [B,T,C]
  attn_k<<<dim3(Tn / 256, Bn * Hn), blk, 0, stream>>>(qb, kb, vb, yb);
  // out = y @ o_proj_w^T + b
  gemm_k<1, 0, 1><<<dim3(128, 16, 1), blk, 0, stream>>>(
      yb, o_proj_w, o_proj_b, out, 8192, 1024, 1024, 0);
}

// Round 2
// 1000.618 us; speedup vs baseline: 1.9411x; 1.9411x over previous
//
#include <hip/hip_runtime.h>
#include <hip/hip_bf16.h>
#include <cstddef>

#define Bn 4
#define Tn 2048
#define Cn 1024
#define Hn 16
#define Rn 256
#define Sn 64
#define Dn 64
static constexpr float SCALE = 0.125f; // 1/sqrt(64)

typedef __attribute__((ext_vector_type(8))) short bf16x8;  // 8 bf16 (4 VGPRs)
typedef __attribute__((ext_vector_type(4))) float f32x4;

__device__ inline short f2bf(float v) {
  return __builtin_bit_cast(short, __float2bfloat16(v));
}

// ---------------------------------------------------------------------------
// Generic fp32-accum tiled GEMM: C = A[M,K] * op(B) (+bias), output type OT.
//   BT=1: B is [N,K] row-major;  BT=0: B is [K,N] row-major.
// SMODE 0: C[m*N+n]                          (latent fp32, final out fp32)
// SMODE 1: v store bf16 [B,H,T,D]: n->(h,d)  C[((b*16+h)*2048+t)*64+d]
// SMODE 2: per-head store (blockIdx.z = h, N==64): C[((b*16+h)*2048+t)*64+n]
// 64x64 tile, BK=16, 256 threads, 4x4 micro-tile per thread.
// ---------------------------------------------------------------------------
template <int BT, int SMODE, int BIAS, typename OT>
__global__ __launch_bounds__(256) void gemm_k(
    const float* __restrict__ A, const float* __restrict__ Bm,
    const float* __restrict__ bias, OT* __restrict__ Cmat,
    int M, int N, int K, int bz_stride) {
  __shared__ float As[16][68];
  __shared__ float Bs[16][68];

  const float* Bp = Bm + (size_t)blockIdx.z * bz_stride;
  const int tid = threadIdx.x;
  const int tx = tid & 15;
  const int ty = tid >> 4;
  const int m0 = blockIdx.x * 64;
  const int n0 = blockIdx.y * 64;

  float acc[4][4] = {};

  for (int k0 = 0; k0 < K; k0 += 16) {
#pragma unroll
    for (int p = 0; p < 4; ++p) {
      int row = p * 16 + ty;
      As[tx][row] = A[(size_t)(m0 + row) * K + k0 + tx];
    }
    if (BT) {
#pragma unroll
      for (int p = 0; p < 4; ++p) {
        int row = p * 16 + ty;
        Bs[tx][row] = Bp[(size_t)(n0 + row) * K + k0 + tx];
      }
    } else {
      int n = tid & 63, kk = tid >> 6;
#pragma unroll
      for (int p = 0; p < 4; ++p) {
        Bs[kk + p * 4][n] = Bp[(size_t)(k0 + kk + p * 4) * N + n0 + n];
      }
    }
    __syncthreads();
#pragma unroll
    for (int kk = 0; kk < 16; ++kk) {
      float a[4], b[4];
#pragma unroll
      for (int i = 0; i < 4; ++i) a[i] = As[kk][ty * 4 + i];
#pragma unroll
      for (int j = 0; j < 4; ++j) b[j] = Bs[kk][tx * 4 + j];
#pragma unroll
      for (int i = 0; i < 4; ++i)
#pragma unroll
        for (int j = 0; j < 4; ++j) acc[i][j] += a[i] * b[j];
    }
    __syncthreads();
  }

#pragma unroll
  for (int i = 0; i < 4; ++i) {
    int m = m0 + ty * 4 + i;
    int b = m >> 11, t = m & 2047;
#pragma unroll
    for (int j = 0; j < 4; ++j) {
      int n = n0 + tx * 4 + j;
      float val = acc[i][j];
      if (BIAS) val += bias[n];
      if (SMODE == 0) {
        Cmat[(size_t)m * N + n] = OT(val);
      } else if (SMODE == 1) {
        int h = n >> 6, d = n & 63;
        Cmat[(((size_t)(b * Hn + h)) * Tn + t) * Dn + d] = OT(val);
      } else {
        Cmat[(((size_t)(b * Hn + (int)blockIdx.z)) * Tn + t) * Sn + n] = OT(val);
      }
    }
  }
}

// ---------------------------------------------------------------------------
// MFMA causal flash attention, bf16 inputs / fp32 accum.
// grid = (T/64, B*H), block = 256 (4 waves). Wave w owns q-rows
// qt*64+w*16 .. +15. Per 64-key tile: QK^T (8 mfma), online softmax
// (shfl_xor over 16-lane col groups), P->LDS (C-layout -> A-layout),
// PV (8 mfma vs LDS V^T).
// mfma_f32_16x16x32_bf16 layouts (m89/m120-verified):
//   A[m=lane&15][k=quad*8+j], B[n=lane&15][k=quad*8+j],
//   C/D: col=lane&15, row=quad*4+reg.
// ---------------------------------------------------------------------------
#define LDK 72  // row pitch in bf16 elems (144 B = 36 dwords -> 2-way max)
__global__ __launch_bounds__(256) void attn_mfma(
    const short* __restrict__ Qg, const short* __restrict__ Kg,
    const short* __restrict__ Vg, float* __restrict__ Y) {
  __shared__ alignas(16) short Ks[64 * LDK];
  __shared__ alignas(16) short Vt[64 * LDK];       // V^T: [d][u]
  __shared__ alignas(16) short Ps[4 * 16 * LDK];   // per-wave P staging

  const int tid = threadIdx.x;
  const int wave = tid >> 6;
  const int lane = tid & 63;
  const int l16 = lane & 15;
  const int quad = lane >> 4;
  const int qt = blockIdx.x, bh = blockIdx.y;
  const size_t base = (size_t)bh * (Tn * 64);

  // Q fragments for this wave's 16 rows (k-step s: d = s*32 + quad*8 ..+7)
  const int qrow = qt * 64 + wave * 16 + l16;
  bf16x8 qf[2];
  qf[0] = *(const bf16x8*)(Qg + base + (size_t)qrow * 64 + quad * 8);
  qf[1] = *(const bf16x8*)(Qg + base + (size_t)qrow * 64 + 32 + quad * 8);

  f32x4 o[4];
#pragma unroll
  for (int i = 0; i < 4; ++i) o[i] = f32x4{0.f, 0.f, 0.f, 0.f};
  float m_r[4], l_r[4];
#pragma unroll
  for (int r = 0; r < 4; ++r) { m_r[r] = -1e30f; l_r[r] = 0.f; }

  for (int j = 0; j <= qt; ++j) {
    // ---- stage K tile [u][d] (vector) and V^T tile [d][u] (transpose) ----
    {
#pragma unroll
      for (int p = 0; p < 2; ++p) {
        int c = tid + p * 256;            // 512 x 16B chunks
        int row = c >> 3, seg = c & 7;
        *(bf16x8*)&Ks[row * LDK + seg * 8] =
            *(const bf16x8*)(Kg + base + ((size_t)(j * 64 + row)) * 64 + seg * 8);
      }
      int u = tid & 63, d0 = (tid >> 6) * 16;
      const short* vp = Vg + base + ((size_t)(j * 64 + u)) * 64 + d0;
      bf16x8 t0 = *(const bf16x8*)vp;
      bf16x8 t1 = *(const bf16x8*)(vp + 8);
#pragma unroll
      for (int i = 0; i < 8; ++i) {
        Vt[(d0 + i) * LDK + u] = t0[i];
        Vt[(d0 + 8 + i) * LDK + u] = t1[i];
      }
    }
    __syncthreads();

    // ---- S = Q K^T (scaled) ----
    f32x4 acc[4];
#pragma unroll
    for (int ct = 0; ct < 4; ++ct) {
      acc[ct] = f32x4{0.f, 0.f, 0.f, 0.f};
#pragma unroll
      for (int s = 0; s < 2; ++s) {
        bf16x8 kf = *(const bf16x8*)&Ks[(ct * 16 + l16) * LDK + s * 32 + quad * 8];
        acc[ct] = __builtin_amdgcn_mfma_f32_16x16x32_bf16(qf[s], kf, acc[ct], 0, 0, 0);
      }
    }

    const bool diag = (j == qt);
    float sv[4][4];
#pragma unroll
    for (int ct = 0; ct < 4; ++ct)
#pragma unroll
      for (int r = 0; r < 4; ++r) {
        float v = acc[ct][r] * SCALE;
        if (diag) {
          int u = ct * 16 + l16;                 // key idx within tile
          int row = wave * 16 + quad * 4 + r;    // q idx within block
          if (u > row) v = -1e30f;
        }
        sv[ct][r] = v;
      }

    // ---- online softmax (per row r; 16-lane col-group reductions) ----
    float alpha[4];
#pragma unroll
    for (int r = 0; r < 4; ++r) {
      float mloc = fmaxf(fmaxf(sv[0][r], sv[1][r]), fmaxf(sv[2][r], sv[3][r]));
#pragma unroll
      for (int off = 1; off < 16; off <<= 1)
        mloc = fmaxf(mloc, __shfl_xor(mloc, off));
      float mnew = fmaxf(m_r[r], mloc);
      alpha[r] = __expf(m_r[r] - mnew);
      m_r[r] = mnew;
      float ls = 0.f;
#pragma unroll
      for (int ct = 0; ct < 4; ++ct) {
        float p = __expf(sv[ct][r] - mnew);
        sv[ct][r] = p;
        ls += p;
      }
#pragma unroll
      for (int off = 1; off < 16; off <<= 1) ls += __shfl_xor(ls, off);
      l_r[r] = l_r[r] * alpha[r] + ls;
#pragma unroll
      for (int dt = 0; dt < 4; ++dt) o[dt][r] *= alpha[r];
    }

    // ---- P: C-layout -> LDS -> A-layout (wave-private region) ----
    short* pw = &Ps[wave * 16 * LDK];
#pragma unroll
    for (int ct = 0; ct < 4; ++ct)
#pragma unroll
      for (int r = 0; r < 4; ++r)
        pw[(quad * 4 + r) * LDK + ct * 16 + l16] = f2bf(sv[ct][r]);

    bf16x8 pf[2];
#pragma unroll
    for (int s = 0; s < 2; ++s)
      pf[s] = *(const bf16x8*)&pw[l16 * LDK + s * 32 + quad * 8];

    // ---- O += P V ----
#pragma unroll
    for (int dt = 0; dt < 4; ++dt)
#pragma unroll
      for (int s = 0; s < 2; ++s) {
        bf16x8 vf = *(const bf16x8*)&Vt[(dt * 16 + l16) * LDK + s * 32 + quad * 8];
        o[dt] = __builtin_amdgcn_mfma_f32_16x16x32_bf16(pf[s], vf, o[dt], 0, 0, 0);
      }
    __syncthreads();
  }

  // ---- epilogue: Y[b, t, h*64 + d] fp32 ----
  const int b = bh >> 4, h = bh & 15;
  float inv[4];
#pragma unroll
  for (int r = 0; r < 4; ++r) inv[r] = 1.f / l_r[r];
#pragma unroll
  for (int dt = 0; dt < 4; ++dt)
#pragma unroll
    for (int r = 0; r < 4; ++r) {
      int t = qt * 64 + wave * 16 + quad * 4 + r;
      Y[((size_t)(b * Tn + t)) * Cn + h * 64 + dt * 16 + l16] = o[dt][r] * inv[r];
    }
}

// ---------------------------------------------------------------------------
extern "C" void kernel_launch(void* const* d_in, const int* in_sizes, int n_in,
                              void* d_out, int out_size, void* d_ws,
                              size_t ws_size, hipStream_t stream) {
  const float* x        = (const float*)d_in[0];
  const float* basis_w  = (const float*)d_in[1];
  const float* u_factor = (const float*)d_in[2];
  const float* v_factor = (const float*)d_in[3];
  const float* v_proj_w = (const float*)d_in[4];
  const float* v_proj_b = (const float*)d_in[5];
  const float* o_proj_w = (const float*)d_in[6];
  const float* o_proj_b = (const float*)d_in[7];
  float* out = (float*)d_out;

  char* ws = (char*)d_ws;
  const size_t BT = (size_t)Bn * Tn;               // 8192
  const size_t BHTS = (size_t)Bn * Hn * Tn * 64;   // 8,388,608
  float* latent = (float*)ws;                       ws += BT * Rn * 4;
  __hip_bfloat16* qb = (__hip_bfloat16*)ws;         ws += BHTS * 2;
  __hip_bfloat16* kb = (__hip_bfloat16*)ws;         ws += BHTS * 2;
  __hip_bfloat16* vb = (__hip_bfloat16*)ws;         ws += BHTS * 2;
  float* yb = (float*)ws;

  dim3 blk(256);
  // latent = x @ basis_w^T : fp32 [8192,256]
  gemm_k<1, 0, 0, float><<<dim3(128, 4, 1), blk, 0, stream>>>(
      x, basis_w, nullptr, latent, 8192, 256, 1024, 0);
  // q = latent @ u[h] -> bf16 [B,H,T,S]
  gemm_k<0, 2, 0, __hip_bfloat16><<<dim3(128, 1, 16), blk, 0, stream>>>(
      latent, u_factor, nullptr, qb, 8192, 64, 256, Rn * Sn);
  // k = latent @ v[h] -> bf16
  gemm_k<0, 2, 0, __hip_bfloat16><<<dim3(128, 1, 16), blk, 0, stream>>>(
      latent, v_factor, nullptr, kb, 8192, 64, 256, Rn * Sn);
  // v = x @ v_proj_w^T + b -> bf16 [B,H,T,D]
  gemm_k<1, 1, 1, __hip_bfloat16><<<dim3(128, 16, 1), blk, 0, stream>>>(
      x, v_proj_w, v_proj_b, vb, 8192, 1024, 1024, 0);
  // attention -> yb fp32 [B,T,C]
  attn_mfma<<<dim3(Tn / 64, Bn * Hn), blk, 0, stream>>>(
      (const short*)qb, (const short*)kb, (const short*)vb, yb);
  // out = yb @ o_proj_w^T + b : fp32
  gemm_k<1, 0, 1, float><<<dim3(128, 16, 1), blk, 0, stream>>>(
      yb, o_proj_w, o_proj_b, out, 8192, 1024, 1024, 0);
}

// Round 3
// 663.039 us; speedup vs baseline: 2.9294x; 1.5091x over previous
//
#include <hip/hip_runtime.h>
#include <hip/hip_bf16.h>
#include <cstddef>
#include <cstdint>

#define Bn 4
#define Tn 2048
#define Cn 1024
#define Hn 16
#define Rn 256
static constexpr float SCALE = 0.125f; // 1/sqrt(64)

typedef __attribute__((ext_vector_type(8))) short bf16x8;  // 8 bf16 (4 VGPRs)
typedef __attribute__((ext_vector_type(4))) float f32x4;

__device__ inline short f2bf(float v) {
  return __builtin_bit_cast(short, __float2bfloat16(v));
}

// async global->LDS, 16 B per lane; LDS dst = wave-uniform base + lane*16
__device__ inline void gld16(const short* g, short* l) {
  __builtin_amdgcn_global_load_lds(
      (const __attribute__((address_space(1))) unsigned*)g,
      (__attribute__((address_space(3))) unsigned*)l, 16, 0, 0);
}

// ---------------------------------------------------------------------------
// fp32 -> bf16 convert, 8 elems/thread
// ---------------------------------------------------------------------------
__global__ __launch_bounds__(256) void cvt_bf16(const float* __restrict__ in,
                                                short* __restrict__ out,
                                                int n8) {
  int i = blockIdx.x * 256 + threadIdx.x;
  if (i >= n8) return;
  const float4* p = (const float4*)in + (size_t)i * 2;
  float4 a = p[0], b = p[1];
  bf16x8 o;
  o[0] = f2bf(a.x); o[1] = f2bf(a.y); o[2] = f2bf(a.z); o[3] = f2bf(a.w);
  o[4] = f2bf(b.x); o[5] = f2bf(b.y); o[6] = f2bf(b.z); o[7] = f2bf(b.w);
  *((bf16x8*)out + i) = o;
}

// ---------------------------------------------------------------------------
// pack u_factor/v_factor [H,R,S] fp32 -> uvb [H,128,R] bf16 (transposed, q|k)
// ---------------------------------------------------------------------------
__global__ __launch_bounds__(256) void uvpack_k(const float* __restrict__ U,
                                                const float* __restrict__ V,
                                                short* __restrict__ out) {
  int idx = blockIdx.x * 256 + threadIdx.x;  // h*32768 + j*256 + r
  int r = idx & 255, j = (idx >> 8) & 127, h = idx >> 15;
  float v = (j < 64) ? U[((size_t)h * 256 + r) * 64 + j]
                     : V[((size_t)h * 256 + r) * 64 + (j - 64)];
  out[idx] = f2bf(v);
}

// ---------------------------------------------------------------------------
// transpose vtmp [bh][t][d] -> VT [bh][d][t]  (bf16, 64x64 tiles)
// ---------------------------------------------------------------------------
__global__ __launch_bounds__(256) void vtrans_k(const short* __restrict__ in,
                                                short* __restrict__ out) {
  __shared__ short L[64 * 72];  // [d][t], pitch 72
  const int tid = threadIdx.x;
  const int t0 = blockIdx.x * 64, bh = blockIdx.y;
#pragma unroll
  for (int p = 0; p < 2; ++p) {
    int c = tid + p * 256;
    int t = c >> 3, dseg = c & 7;
    bf16x8 v = *(const bf16x8*)(in + ((size_t)bh * Tn + t0 + t) * 64 + dseg * 8);
#pragma unroll
    for (int i = 0; i < 8; ++i) L[(dseg * 8 + i) * 72 + t] = v[i];
  }
  __syncthreads();
#pragma unroll
  for (int p = 0; p < 2; ++p) {
    int c = tid + p * 256;
    int d = c >> 3, tseg = c & 7;
    bf16x8 v = *(const bf16x8*)&L[d * 72 + tseg * 8];
    *(bf16x8*)(out + ((size_t)bh * 64 + d) * Tn + t0 + tseg * 8) = v;
  }
}

// ---------------------------------------------------------------------------
// bf16 MFMA GEMM, m97 recipe: 128x128 tile, BK=32, 4 waves (2x2 of 64x64),
// global_load_lds 16B staging, 8 ds_read_b128 + 16 mfma per K-iter per wave.
// A [M,K], B [N,K] (pre-transposed where needed), accum fp32.
// SMODE 0: bf16 C0[m*N+n]
// SMODE 1: per-head q|k split (blockIdx.z=h, N=128):
//          n<64 -> Q[(bh*T+t)*64+n], else K[(bh*T+t)*64+n-64]
// SMODE 2: bf16 [B,H,T,D]: n->(h,d): C0[((b*16+h)*T+t)*64+d]
// SMODE 3: fp32 C0[m*N+n]
// ---------------------------------------------------------------------------
template <int SMODE, int BIAS>
__global__ __launch_bounds__(256) void gemm_mfma(
    const short* __restrict__ A, const short* __restrict__ Bm,
    const float* __restrict__ bias, void* __restrict__ C0,
    void* __restrict__ C1, int M, int N, int K, int bstride) {
  __shared__ short As[128 * 32];
  __shared__ short Bs[128 * 32];
  const int tid = threadIdx.x;
  const int lane = tid & 63, l16 = lane & 15, quad = lane >> 4;
  const int wave = tid >> 6;
  const int wm = (wave >> 1) * 64, wn = (wave & 1) * 64;
  const int m0 = blockIdx.x * 128, n0 = blockIdx.y * 128;
  const short* Bp = Bm + (size_t)blockIdx.z * bstride;

  f32x4 acc[4][4];
#pragma unroll
  for (int i = 0; i < 4; ++i)
#pragma unroll
    for (int j = 0; j < 4; ++j) acc[i][j] = f32x4{0.f, 0.f, 0.f, 0.f};

  const int arow = tid >> 2, achk = (tid & 3) * 8;
  for (int k0 = 0; k0 < K; k0 += 32) {
#pragma unroll
    for (int p = 0; p < 2; ++p) {
      gld16(A + (size_t)(m0 + p * 64 + arow) * K + k0 + achk,
            As + p * 2048 + tid * 8);
      gld16(Bp + (size_t)(n0 + p * 64 + arow) * K + k0 + achk,
            Bs + p * 2048 + tid * 8);
    }
    __syncthreads();
    bf16x8 af[4], bf[4];
#pragma unroll
    for (int i = 0; i < 4; ++i)
      af[i] = *(const bf16x8*)&As[(wm + i * 16 + l16) * 32 + quad * 8];
#pragma unroll
    for (int j = 0; j < 4; ++j)
      bf[j] = *(const bf16x8*)&Bs[(wn + j * 16 + l16) * 32 + quad * 8];
#pragma unroll
    for (int i = 0; i < 4; ++i)
#pragma unroll
      for (int j = 0; j < 4; ++j)
        acc[i][j] =
            __builtin_amdgcn_mfma_f32_16x16x32_bf16(af[i], bf[j], acc[i][j], 0, 0, 0);
    __syncthreads();
  }

  float bj[4];
#pragma unroll
  for (int j = 0; j < 4; ++j)
    bj[j] = BIAS ? bias[n0 + wn + j * 16 + l16] : 0.f;

#pragma unroll
  for (int i = 0; i < 4; ++i) {
#pragma unroll
    for (int r = 0; r < 4; ++r) {
      int m = m0 + wm + i * 16 + quad * 4 + r;
      int b = m >> 11, t = m & 2047;
#pragma unroll
      for (int j = 0; j < 4; ++j) {
        int n = n0 + wn + j * 16 + l16;
        float val = acc[i][j][r] + bj[j];
        if (SMODE == 0) {
          ((short*)C0)[(size_t)m * N + n] = f2bf(val);
        } else if (SMODE == 1) {
          int bh = b * Hn + (int)blockIdx.z;
          short* dst = (short*)(n < 64 ? C0 : C1);
          dst[((size_t)bh * Tn + t) * 64 + (n & 63)] = f2bf(val);
        } else if (SMODE == 2) {
          int h = n >> 6, d = n & 63;
          ((short*)C0)[(((size_t)(b * Hn + h)) * Tn + t) * 64 + d] = f2bf(val);
        } else {
          ((float*)C0)[(size_t)m * N + n] = val;
        }
      }
    }
  }
}

// ---------------------------------------------------------------------------
// Barrier-free MFMA flash attention (no-max softmax: scores |s|<~0.5, exp-safe,
// mathematically identical to shifted softmax).
// grid = (32, B*H), block = 256 = 4 independent waves; wave w owns q-rows
// qt16*16..+15 with qt16 = (31-blockIdx.x)*4 + w (heavy tiles dispatch first).
// K frags and V^T frags loaded straight from global (L2/L3-resident).
// P transform C-layout -> A-layout through per-wave LDS (pitch 80).
// ---------------------------------------------------------------------------
__global__ __launch_bounds__(256) void atn2(const short* __restrict__ Qg,
                                            const short* __restrict__ Kg,
                                            const short* __restrict__ VTg,
                                            short* __restrict__ Yb) {
  __shared__ short Ps[4 * 16 * 80];
  const int tid = threadIdx.x;
  const int wave = tid >> 6, lane = tid & 63;
  const int l16 = lane & 15, quad = lane >> 4;
  const int qg = gridDim.x - 1 - blockIdx.x;
  const int qt16 = qg * 4 + wave;
  const int bh = blockIdx.y;
  const int trow = qt16 * 16;
  const size_t kb = (size_t)bh * Tn * 64;   // K/Q base
  const size_t vb = (size_t)bh * 64 * Tn;   // VT base

  bf16x8 qf[2];
#pragma unroll
  for (int s = 0; s < 2; ++s)
    qf[s] = *(const bf16x8*)(Qg + kb + (size_t)(trow + l16) * 64 + s * 32 + quad * 8);

  f32x4 o[4];
#pragma unroll
  for (int i = 0; i < 4; ++i) o[i] = f32x4{0.f, 0.f, 0.f, 0.f};
  float lp[4] = {0.f, 0.f, 0.f, 0.f};

  short* pw = &Ps[wave * 16 * 80];
  const int jmax = qt16 >> 2;

  for (int j = 0; j <= jmax; ++j) {
    bf16x8 kf[4][2], vf[4][2];
#pragma unroll
    for (int ct = 0; ct < 4; ++ct)
#pragma unroll
      for (int s = 0; s < 2; ++s)
        kf[ct][s] = *(const bf16x8*)(Kg + kb +
            (size_t)(j * 64 + ct * 16 + l16) * 64 + s * 32 + quad * 8);
#pragma unroll
    for (int dt = 0; dt < 4; ++dt)
#pragma unroll
      for (int s = 0; s < 2; ++s)
        vf[dt][s] = *(const bf16x8*)(VTg + vb +
            (size_t)(dt * 16 + l16) * Tn + j * 64 + s * 32 + quad * 8);

    f32x4 sa[4];
#pragma unroll
    for (int ct = 0; ct < 4; ++ct) {
      sa[ct] = f32x4{0.f, 0.f, 0.f, 0.f};
#pragma unroll
      for (int s = 0; s < 2; ++s)
        sa[ct] = __builtin_amdgcn_mfma_f32_16x16x32_bf16(qf[s], kf[ct][s], sa[ct], 0, 0, 0);
    }

    // p = exp(s*SCALE) with causal mask; accumulate per-lane l partials
#pragma unroll
    for (int ct = 0; ct < 4; ++ct) {
      int u = j * 64 + ct * 16 + l16;
#pragma unroll
      for (int r = 0; r < 4; ++r) {
        int t = trow + quad * 4 + r;
        float e = (u <= t) ? __expf(sa[ct][r] * SCALE) : 0.f;
        lp[r] += e;
        pw[(quad * 4 + r) * 80 + ct * 16 + l16] = f2bf(e);
      }
    }

    bf16x8 pf[2];
#pragma unroll
    for (int s = 0; s < 2; ++s)
      pf[s] = *(const bf16x8*)&pw[l16 * 80 + s * 32 + quad * 8];

#pragma unroll
    for (int dt = 0; dt < 4; ++dt)
#pragma unroll
      for (int s = 0; s < 2; ++s)
        o[dt] = __builtin_amdgcn_mfma_f32_16x16x32_bf16(pf[s], vf[dt][s], o[dt], 0, 0, 0);
  }

  // finalize l (sum over the 16-lane column group) and scale O
  float inv[4];
#pragma unroll
  for (int r = 0; r < 4; ++r) {
    float l = lp[r];
    l += __shfl_xor(l, 1);
    l += __shfl_xor(l, 2);
    l += __shfl_xor(l, 4);
    l += __shfl_xor(l, 8);
    inv[r] = 1.f / l;
  }

  // epilogue: bounce through LDS (reuse pw) for coalesced bf16 row stores
#pragma unroll
  for (int dt = 0; dt < 4; ++dt)
#pragma unroll
    for (int r = 0; r < 4; ++r)
      pw[(quad * 4 + r) * 80 + dt * 16 + l16] = f2bf(o[dt][r] * inv[r]);

  const int row = lane >> 2, cseg = lane & 3;
  bf16x8 y0 = *(const bf16x8*)&pw[row * 80 + cseg * 16];
  bf16x8 y1 = *(const bf16x8*)&pw[row * 80 + cseg * 16 + 8];
  const int b = bh >> 4, h = bh & 15;
  short* dst = Yb + ((size_t)(b * Tn + trow + row)) * Cn + h * 64 + cseg * 16;
  *(bf16x8*)dst = y0;
  *(bf16x8*)(dst + 8) = y1;
}

// ---------------------------------------------------------------------------
extern "C" void kernel_launch(void* const* d_in, const int* in_sizes, int n_in,
                              void* d_out, int out_size, void* d_ws,
                              size_t ws_size, hipStream_t stream) {
  const float* x        = (const float*)d_in[0];
  const float* basis_w  = (const float*)d_in[1];
  const float* u_factor = (const float*)d_in[2];
  const float* v_factor = (const float*)d_in[3];
  const float* v_proj_w = (const float*)d_in[4];
  const float* v_proj_b = (const float*)d_in[5];
  const float* o_proj_w = (const float*)d_in[6];
  const float* o_proj_b = (const float*)d_in[7];
  float* out = (float*)d_out;

  char* ws = (char*)d_ws;
  const size_t NX = (size_t)Bn * Tn * Cn;          // 8,388,608
  short* xb      = (short*)ws; ws += NX * 2;       // [8192,1024]
  short* bwb     = (short*)ws; ws += (size_t)Rn * Cn * 2;        // [256,1024]
  short* vpb     = (short*)ws; ws += (size_t)Cn * Cn * 2;        // [1024,1024]
  short* opb     = (short*)ws; ws += (size_t)Cn * Cn * 2;
  short* uvb     = (short*)ws; ws += (size_t)Hn * 128 * Rn * 2;  // [16,128,256]
  short* latentb = (short*)ws; ws += (size_t)Bn * Tn * Rn * 2;   // [8192,256]
  short* Qb      = (short*)ws; ws += NX * 2;       // [bh,T,64]
  short* Kb      = (short*)ws; ws += NX * 2;
  short* vtmp    = (short*)ws; ws += NX * 2;       // [bh,T,64]
  short* VTb     = (short*)ws; ws += NX * 2;       // [bh,64,T]
  short* yb      = (short*)ws;                     // [8192,1024]

  dim3 blk(256);
  cvt_bf16<<<dim3(4096), blk, 0, stream>>>(x, xb, (int)(NX / 8));
  cvt_bf16<<<dim3(128), blk, 0, stream>>>(basis_w, bwb, Rn * Cn / 8);
  cvt_bf16<<<dim3(512), blk, 0, stream>>>(v_proj_w, vpb, Cn * Cn / 8);
  cvt_bf16<<<dim3(512), blk, 0, stream>>>(o_proj_w, opb, Cn * Cn / 8);
  uvpack_k<<<dim3(2048), blk, 0, stream>>>(u_factor, v_factor, uvb);

  // latent = x @ basis^T : bf16 [8192,256]
  gemm_mfma<0, 0><<<dim3(64, 2, 1), blk, 0, stream>>>(
      xb, bwb, nullptr, latentb, nullptr, 8192, 256, 1024, 0);
  // q|k = latent @ uv[h]^T : per-head split into Qb, Kb
  gemm_mfma<1, 0><<<dim3(64, 1, 16), blk, 0, stream>>>(
      latentb, uvb, nullptr, Qb, Kb, 8192, 128, 256, 128 * 256);
  // v = x @ v_proj^T + b -> [bh,T,64]
  gemm_mfma<2, 1><<<dim3(64, 8, 1), blk, 0, stream>>>(
      xb, vpb, v_proj_b, vtmp, nullptr, 8192, 1024, 1024, 0);
  // V^T [bh,64,T]
  vtrans_k<<<dim3(32, 64), blk, 0, stream>>>(vtmp, VTb);
  // attention -> yb bf16 [8192,1024]
  atn2<<<dim3(32, 64), blk, 0, stream>>>(Qb, Kb, VTb, yb);
  // out = yb @ o_proj^T + b : fp32
  gemm_mfma<3, 1><<<dim3(64, 8, 1), blk, 0, stream>>>(
      yb, opb, o_proj_b, out, nullptr, 8192, 1024, 1024, 0);
}

// Round 4
// 363.469 us; speedup vs baseline: 5.3437x; 1.8242x over previous
//
#include <hip/hip_runtime.h>
#include <hip/hip_bf16.h>
#include <cstddef>
#include <cstdint>

#define Bn 4
#define Tn 2048
#define Cn 1024
#define Hn 16
#define Rn 256
static constexpr float SCALE = 0.125f; // 1/sqrt(64)

typedef __attribute__((ext_vector_type(8))) short bf16x8;  // 8 bf16 (4 VGPRs)
typedef __attribute__((ext_vector_type(4))) float f32x4;

__device__ inline short f2bf(float v) {
  return __builtin_bit_cast(short, __float2bfloat16(v));
}

// async global->LDS, 16 B per lane; LDS dst = wave-uniform base + lane*16
__device__ inline void gld16(const short* g, short* l) {
  __builtin_amdgcn_global_load_lds(
      (const __attribute__((address_space(1))) unsigned*)g,
      (__attribute__((address_space(3))) unsigned*)l, 16, 0, 0);
}

// ---------------------------------------------------------------------------
// fp32 -> bf16 convert, 8 elems/thread
// ---------------------------------------------------------------------------
__global__ __launch_bounds__(256) void cvt_bf16(const float* __restrict__ in,
                                                short* __restrict__ out,
                                                int n8) {
  int i = blockIdx.x * 256 + threadIdx.x;
  if (i >= n8) return;
  const float4* p = (const float4*)in + (size_t)i * 2;
  float4 a = p[0], b = p[1];
  bf16x8 o;
  o[0] = f2bf(a.x); o[1] = f2bf(a.y); o[2] = f2bf(a.z); o[3] = f2bf(a.w);
  o[4] = f2bf(b.x); o[5] = f2bf(b.y); o[6] = f2bf(b.z); o[7] = f2bf(b.w);
  *((bf16x8*)out + i) = o;
}

// ---------------------------------------------------------------------------
// pack u_factor/v_factor [H,R,S] fp32 -> uvb [H,128,R] bf16 (transposed, q|k)
// ---------------------------------------------------------------------------
__global__ __launch_bounds__(256) void uvpack_k(const float* __restrict__ U,
                                                const float* __restrict__ V,
                                                short* __restrict__ out) {
  int idx = blockIdx.x * 256 + threadIdx.x;  // h*32768 + j*256 + r
  int r = idx & 255, j = (idx >> 8) & 127, h = idx >> 15;
  float v = (j < 64) ? U[((size_t)h * 256 + r) * 64 + j]
                     : V[((size_t)h * 256 + r) * 64 + (j - 64)];
  out[idx] = f2bf(v);
}

// ---------------------------------------------------------------------------
// transpose vtmp [bh][t][d] -> VT [bh][d][t]  (bf16, 64x64 tiles)
// ---------------------------------------------------------------------------
__global__ __launch_bounds__(256) void vtrans_k(const short* __restrict__ in,
                                                short* __restrict__ out) {
  __shared__ short L[64 * 72];  // [d][t], pitch 72
  const int tid = threadIdx.x;
  const int t0 = blockIdx.x * 64, bh = blockIdx.y;
#pragma unroll
  for (int p = 0; p < 2; ++p) {
    int c = tid + p * 256;
    int t = c >> 3, dseg = c & 7;
    bf16x8 v = *(const bf16x8*)(in + ((size_t)bh * Tn + t0 + t) * 64 + dseg * 8);
#pragma unroll
    for (int i = 0; i < 8; ++i) L[(dseg * 8 + i) * 72 + t] = v[i];
  }
  __syncthreads();
#pragma unroll
  for (int p = 0; p < 2; ++p) {
    int c = tid + p * 256;
    int d = c >> 3, tseg = c & 7;
    bf16x8 v = *(const bf16x8*)&L[d * 72 + tseg * 8];
    *(bf16x8*)(out + ((size_t)bh * 64 + d) * Tn + t0 + tseg * 8) = v;
  }
}

// ---------------------------------------------------------------------------
// bf16 MFMA GEMM (m97 recipe): 128x128 tile, BK=32, 4 waves (2x2 of 64x64),
// global_load_lds 16B staging, accum fp32.
// SMODE 0: bf16 C0[m*N+n]
// SMODE 1: per-head q|k split (blockIdx.z=h, N=128)
// SMODE 2: bf16 [B,H,T,D]
// SMODE 3: fp32 C0[m*N+n]
// ---------------------------------------------------------------------------
template <int SMODE, int BIAS>
__global__ __launch_bounds__(256) void gemm_mfma(
    const short* __restrict__ A, const short* __restrict__ Bm,
    const float* __restrict__ bias, void* __restrict__ C0,
    void* __restrict__ C1, int M, int N, int K, int bstride) {
  __shared__ short As[128 * 32];
  __shared__ short Bs[128 * 32];
  const int tid = threadIdx.x;
  const int lane = tid & 63, l16 = lane & 15, quad = lane >> 4;
  const int wave = tid >> 6;
  const int wm = (wave >> 1) * 64, wn = (wave & 1) * 64;
  const int m0 = blockIdx.x * 128, n0 = blockIdx.y * 128;
  const short* Bp = Bm + (size_t)blockIdx.z * bstride;

  f32x4 acc[4][4];
#pragma unroll
  for (int i = 0; i < 4; ++i)
#pragma unroll
    for (int j = 0; j < 4; ++j) acc[i][j] = f32x4{0.f, 0.f, 0.f, 0.f};

  const int arow = tid >> 2, achk = (tid & 3) * 8;
  for (int k0 = 0; k0 < K; k0 += 32) {
#pragma unroll
    for (int p = 0; p < 2; ++p) {
      gld16(A + (size_t)(m0 + p * 64 + arow) * K + k0 + achk,
            As + p * 2048 + tid * 8);
      gld16(Bp + (size_t)(n0 + p * 64 + arow) * K + k0 + achk,
            Bs + p * 2048 + tid * 8);
    }
    __syncthreads();
    bf16x8 af[4], bf[4];
#pragma unroll
    for (int i = 0; i < 4; ++i)
      af[i] = *(const bf16x8*)&As[(wm + i * 16 + l16) * 32 + quad * 8];
#pragma unroll
    for (int j = 0; j < 4; ++j)
      bf[j] = *(const bf16x8*)&Bs[(wn + j * 16 + l16) * 32 + quad * 8];
#pragma unroll
    for (int i = 0; i < 4; ++i)
#pragma unroll
      for (int j = 0; j < 4; ++j)
        acc[i][j] =
            __builtin_amdgcn_mfma_f32_16x16x32_bf16(af[i], bf[j], acc[i][j], 0, 0, 0);
    __syncthreads();
  }

  float bj[4];
#pragma unroll
  for (int j = 0; j < 4; ++j)
    bj[j] = BIAS ? bias[n0 + wn + j * 16 + l16] : 0.f;

#pragma unroll
  for (int i = 0; i < 4; ++i) {
#pragma unroll
    for (int r = 0; r < 4; ++r) {
      int m = m0 + wm + i * 16 + quad * 4 + r;
      int b = m >> 11, t = m & 2047;
#pragma unroll
      for (int j = 0; j < 4; ++j) {
        int n = n0 + wn + j * 16 + l16;
        float val = acc[i][j][r] + bj[j];
        if (SMODE == 0) {
          ((short*)C0)[(size_t)m * N + n] = f2bf(val);
        } else if (SMODE == 1) {
          int bh = b * Hn + (int)blockIdx.z;
          short* dst = (short*)(n < 64 ? C0 : C1);
          dst[((size_t)bh * Tn + t) * 64 + (n & 63)] = f2bf(val);
        } else if (SMODE == 2) {
          int h = n >> 6, d = n & 63;
          ((short*)C0)[(((size_t)(b * Hn + h)) * Tn + t) * 64 + d] = f2bf(val);
        } else {
          ((float*)C0)[(size_t)m * N + n] = val;
        }
      }
    }
  }
}

// ---------------------------------------------------------------------------
// MFMA flash attention v4: LDS-staged K/V shared by 128 q-rows per block.
// grid = (16, B*H) heavy-first; block = 256 (4 waves); wave w owns q-rows
// qt*128 + w*32 .. +31 (2 MFMA row-groups).
// Per 64-key tile j: stage K[u][d] + VT[d][u] (global_load_lds, XOR chunk
// swizzle slot = seg^(row&7) for bank-balanced b128 frag reads), barrier,
// frag-read K/V, barrier, prefetch tile j+1 (overlaps compute), then
// QK mfma -> exp (no-max softmax: |s|<~0.5) -> P via per-wave LDS -> PV mfma.
// ---------------------------------------------------------------------------
#define PP 72  // P staging pitch (shorts)
__global__ __launch_bounds__(256) void atn3(const short* __restrict__ Qg,
                                            const short* __restrict__ Kg,
                                            const short* __restrict__ VTg,
                                            short* __restrict__ Yb) {
  __shared__ short Ks[64 * 64];
  __shared__ short Vt[64 * 64];
  __shared__ short Ps[4 * 32 * PP];

  const int tid = threadIdx.x;
  const int wave = tid >> 6, lane = tid & 63;
  const int l16 = lane & 15, quad = lane >> 4;
  const int qt = gridDim.x - 1 - blockIdx.x;  // heavy tiles first
  const int bh = blockIdx.y;
  const int wtrow = qt * 128 + wave * 32;
  const size_t kb = (size_t)bh * Tn * 64;
  const size_t vb = (size_t)bh * 64 * Tn;
  const int jmax = 2 * qt + 1;

  // Q fragments: 2 row-groups x 2 k-steps
  bf16x8 qf[2][2];
#pragma unroll
  for (int rg = 0; rg < 2; ++rg)
#pragma unroll
    for (int s = 0; s < 2; ++s)
      qf[rg][s] = *(const bf16x8*)(Qg + kb +
          (size_t)(wtrow + rg * 16 + l16) * 64 + s * 32 + quad * 8);

  f32x4 o[2][4];
#pragma unroll
  for (int rg = 0; rg < 2; ++rg)
#pragma unroll
    for (int dt = 0; dt < 4; ++dt) o[rg][dt] = f32x4{0.f, 0.f, 0.f, 0.f};
  float lp[2][4] = {{0.f, 0.f, 0.f, 0.f}, {0.f, 0.f, 0.f, 0.f}};

  // staging: 512 chunks of 16B each for K and VT; slot = seg ^ (row&7)
  const int c0r = tid >> 3;                 // rows handled by this thread
  const int c0slot = tid & 7;
#define STAGE(j)                                                              \
  {                                                                           \
    _Pragma("unroll") for (int p = 0; p < 2; ++p) {                           \
      int row = c0r + p * 32;                                                 \
      int seg = c0slot ^ (row & 7);                                           \
      gld16(Kg + kb + (size_t)((j) * 64 + row) * 64 + seg * 8,                \
            Ks + (tid + p * 256) * 8);                                        \
      gld16(VTg + vb + (size_t)row * Tn + (j) * 64 + seg * 8,                 \
            Vt + (tid + p * 256) * 8);                                        \
    }                                                                         \
  }

  STAGE(0);
  short* pw = &Ps[wave * 32 * PP];
  const int xs = l16 & 7;  // read-side de-swizzle key

  for (int j = 0; j <= jmax; ++j) {
    __syncthreads();  // tile j resident in LDS
    const bool act1 = (j * 64 <= wtrow + 31);
    const bool act0 = (j * 64 <= wtrow + 15);
    f32x4 sa[2][4];
    bf16x8 vf[4][2];
    if (act1) {
      // K frags + QK^T
      bf16x8 kf[4][2];
#pragma unroll
      for (int ct = 0; ct < 4; ++ct)
#pragma unroll
        for (int s = 0; s < 2; ++s)
          kf[ct][s] = *(const bf16x8*)&Ks[(ct * 16 + l16) * 64 +
                                          ((s * 4 + quad) ^ xs) * 8];
#pragma unroll
      for (int rg = 0; rg < 2; ++rg) {
        if (rg == 0 && !act0) continue;
#pragma unroll
        for (int ct = 0; ct < 4; ++ct) {
          sa[rg][ct] = f32x4{0.f, 0.f, 0.f, 0.f};
#pragma unroll
          for (int s = 0; s < 2; ++s)
            sa[rg][ct] = __builtin_amdgcn_mfma_f32_16x16x32_bf16(
                qf[rg][s], kf[ct][s], sa[rg][ct], 0, 0, 0);
        }
      }
      // V^T frags
#pragma unroll
      for (int dt = 0; dt < 4; ++dt)
#pragma unroll
        for (int s = 0; s < 2; ++s)
          vf[dt][s] = *(const bf16x8*)&Vt[(dt * 16 + l16) * 64 +
                                          ((s * 4 + quad) ^ xs) * 8];
    }
    __syncthreads();  // all waves done reading Ks/Vt
    if (j < jmax) STAGE(j + 1);  // prefetch overlaps compute below

    if (act1) {
#pragma unroll
      for (int rg = 0; rg < 2; ++rg) {
        if (rg == 0 && !act0) continue;
        const int rbase = wtrow + rg * 16;
        const bool full = (j * 64 + 63 <= rbase);  // no masking needed
#pragma unroll
        for (int ct = 0; ct < 4; ++ct) {
          const int u = j * 64 + ct * 16 + l16;
#pragma unroll
          for (int r = 0; r < 4; ++r) {
            float e;
            if (full) {
              e = __expf(sa[rg][ct][r] * SCALE);
            } else {
              const int t = rbase + quad * 4 + r;
              e = (u <= t) ? __expf(sa[rg][ct][r] * SCALE) : 0.f;
            }
            lp[rg][r] += e;
            pw[(rg * 16 + quad * 4 + r) * PP + ct * 16 + l16] = f2bf(e);
          }
        }
        bf16x8 pf[2];
#pragma unroll
        for (int s = 0; s < 2; ++s)
          pf[s] = *(const bf16x8*)&pw[(rg * 16 + l16) * PP + s * 32 + quad * 8];
#pragma unroll
        for (int dt = 0; dt < 4; ++dt)
#pragma unroll
          for (int s = 0; s < 2; ++s)
            o[rg][dt] = __builtin_amdgcn_mfma_f32_16x16x32_bf16(
                pf[s], vf[dt][s], o[rg][dt], 0, 0, 0);
      }
    }
  }

  // finalize l, write Y through LDS bounce for coalesced stores
  const int b = bh >> 4, h = bh & 15;
#pragma unroll
  for (int rg = 0; rg < 2; ++rg) {
    float inv[4];
#pragma unroll
    for (int r = 0; r < 4; ++r) {
      float l = lp[rg][r];
      l += __shfl_xor(l, 1);
      l += __shfl_xor(l, 2);
      l += __shfl_xor(l, 4);
      l += __shfl_xor(l, 8);
      inv[r] = 1.f / l;
    }
#pragma unroll
    for (int dt = 0; dt < 4; ++dt)
#pragma unroll
      for (int r = 0; r < 4; ++r)
        pw[(rg * 16 + quad * 4 + r) * PP + dt * 16 + l16] =
            f2bf(o[rg][dt][r] * inv[r]);
    const int row = lane >> 2, cseg = lane & 3;
    bf16x8 y0 = *(const bf16x8*)&pw[(rg * 16 + row) * PP + cseg * 16];
    bf16x8 y1 = *(const bf16x8*)&pw[(rg * 16 + row) * PP + cseg * 16 + 8];
    short* dst = Yb + ((size_t)(b * Tn + wtrow + rg * 16 + row)) * Cn +
                 h * 64 + cseg * 16;
    *(bf16x8*)dst = y0;
    *(bf16x8*)(dst + 8) = y1;
  }
}

// ---------------------------------------------------------------------------
extern "C" void kernel_launch(void* const* d_in, const int* in_sizes, int n_in,
                              void* d_out, int out_size, void* d_ws,
                              size_t ws_size, hipStream_t stream) {
  const float* x        = (const float*)d_in[0];
  const float* basis_w  = (const float*)d_in[1];
  const float* u_factor = (const float*)d_in[2];
  const float* v_factor = (const float*)d_in[3];
  const float* v_proj_w = (const float*)d_in[4];
  const float* v_proj_b = (const float*)d_in[5];
  const float* o_proj_w = (const float*)d_in[6];
  const float* o_proj_b = (const float*)d_in[7];
  float* out = (float*)d_out;

  char* ws = (char*)d_ws;
  const size_t NX = (size_t)Bn * Tn * Cn;          // 8,388,608
  short* xb      = (short*)ws; ws += NX * 2;       // [8192,1024]
  short* bwb     = (short*)ws; ws += (size_t)Rn * Cn * 2;        // [256,1024]
  short* vpb     = (short*)ws; ws += (size_t)Cn * Cn * 2;        // [1024,1024]
  short* opb     = (short*)ws; ws += (size_t)Cn * Cn * 2;
  short* uvb     = (short*)ws; ws += (size_t)Hn * 128 * Rn * 2;  // [16,128,256]
  short* latentb = (short*)ws; ws += (size_t)Bn * Tn * Rn * 2;   // [8192,256]
  short* Qb      = (short*)ws; ws += NX * 2;       // [bh,T,64]
  short* Kb      = (short*)ws; ws += NX * 2;
  short* vtmp    = (short*)ws; ws += NX * 2;       // [bh,T,64]
  short* VTb     = (short*)ws; ws += NX * 2;       // [bh,64,T]
  short* yb      = (short*)ws;                     // [8192,1024]

  dim3 blk(256);
  cvt_bf16<<<dim3(4096), blk, 0, stream>>>(x, xb, (int)(NX / 8));
  cvt_bf16<<<dim3(128), blk, 0, stream>>>(basis_w, bwb, Rn * Cn / 8);
  cvt_bf16<<<dim3(512), blk, 0, stream>>>(v_proj_w, vpb, Cn * Cn / 8);
  cvt_bf16<<<dim3(512), blk, 0, stream>>>(o_proj_w, opb, Cn * Cn / 8);
  uvpack_k<<<dim3(2048), blk, 0, stream>>>(u_factor, v_factor, uvb);

  // latent = x @ basis^T : bf16 [8192,256]
  gemm_mfma<0, 0><<<dim3(64, 2, 1), blk, 0, stream>>>(
      xb, bwb, nullptr, latentb, nullptr, 8192, 256, 1024, 0);
  // q|k = latent @ uv[h]^T : per-head split into Qb, Kb
  gemm_mfma<1, 0><<<dim3(64, 1, 16), blk, 0, stream>>>(
      latentb, uvb, nullptr, Qb, Kb, 8192, 128, 256, 128 * 256);
  // v = x @ v_proj^T + b -> [bh,T,64]
  gemm_mfma<2, 1><<<dim3(64, 8, 1), blk, 0, stream>>>(
      xb, vpb, v_proj_b, vtmp, nullptr, 8192, 1024, 1024, 0);
  // V^T [bh,64,T]
  vtrans_k<<<dim3(32, 64), blk, 0, stream>>>(vtmp, VTb);
  // attention -> yb bf16 [8192,1024]
  atn3<<<dim3(16, 64), blk, 0, stream>>>(Qb, Kb, VTb, yb);
  // out = yb @ o_proj^T + b : fp32
  gemm_mfma<3, 1><<<dim3(64, 8, 1), blk, 0, stream>>>(
      yb, opb, o_proj_b, out, nullptr, 8192, 1024, 1024, 0);
}

// Round 5
// 322.966 us; speedup vs baseline: 6.0139x; 1.1254x over previous
//
#include <hip/hip_runtime.h>
#include <hip/hip_bf16.h>
#include <cstddef>
#include <cstdint>

#define Bn 4
#define Tn 2048
#define Cn 1024
#define Hn 16
#define Rn 256
static constexpr float SCALE = 0.125f; // 1/sqrt(64)

typedef __attribute__((ext_vector_type(8))) short bf16x8;  // 8 bf16 (4 VGPRs)
typedef __attribute__((ext_vector_type(4))) float f32x4;

__device__ inline short f2bf(float v) {
  return __builtin_bit_cast(short, __float2bfloat16(v));
}
__device__ inline float bf2f(short s) {
  return __builtin_bit_cast(float, (unsigned)(unsigned short)s << 16);
}

// async global->LDS, 16 B per lane; LDS dst = wave-uniform base + lane*16
__device__ inline void gld16(const short* g, short* l) {
  __builtin_amdgcn_global_load_lds(
      (const __attribute__((address_space(1))) unsigned*)g,
      (__attribute__((address_space(3))) unsigned*)l, 16, 0, 0);
}

// ---------------------------------------------------------------------------
// Fused fp32->bf16 convert for x|basis|vproj|oproj (contiguous dst in ws)
// + uv pack: u,v [H,R,S] -> uvb [H,128,R] (transposed, q|k concat).
// ---------------------------------------------------------------------------
#define NCVT 1343488  // 8-elem units: x 1048576 | basis 32768 | vp 131072 | op 131072
__global__ __launch_bounds__(256) void cvtall(
    const float* __restrict__ x, const float* __restrict__ basis,
    const float* __restrict__ vproj, const float* __restrict__ oproj,
    const float* __restrict__ U, const float* __restrict__ V,
    short* __restrict__ dst, short* __restrict__ uvb) {
  int gid = blockIdx.x * 256 + threadIdx.x;
  if (gid < NCVT) {
    const float* src;
    int off;
    if (gid < 1048576) { src = x; off = gid; }
    else if (gid < 1081344) { src = basis; off = gid - 1048576; }
    else if (gid < 1212416) { src = vproj; off = gid - 1081344; }
    else { src = oproj; off = gid - 1212416; }
    const float4* p = (const float4*)src + (size_t)off * 2;
    float4 a = p[0], b = p[1];
    bf16x8 o;
    o[0] = f2bf(a.x); o[1] = f2bf(a.y); o[2] = f2bf(a.z); o[3] = f2bf(a.w);
    o[4] = f2bf(b.x); o[5] = f2bf(b.y); o[6] = f2bf(b.z); o[7] = f2bf(b.w);
    *((bf16x8*)dst + gid) = o;
  } else if (gid < NCVT + 65536) {
    int base = (gid - NCVT) * 8;
    int r0 = base & 255, j = (base >> 8) & 127, h = base >> 15;
    bf16x8 o;
#pragma unroll
    for (int i = 0; i < 8; ++i) {
      int r = r0 + i;
      float v = (j < 64) ? U[((size_t)h * 256 + r) * 64 + j]
                         : V[((size_t)h * 256 + r) * 64 + (j - 64)];
      o[i] = f2bf(v);
    }
    *(bf16x8*)(uvb + base) = o;
  }
}

// ---------------------------------------------------------------------------
// transpose vtmp [bh][t][d] -> VT [bh][d][t]  (bf16, 64x64 tiles)
// ---------------------------------------------------------------------------
__global__ __launch_bounds__(256) void vtrans_k(const short* __restrict__ in,
                                                short* __restrict__ out) {
  __shared__ short L[64 * 72];
  const int tid = threadIdx.x;
  const int t0 = blockIdx.x * 64, bh = blockIdx.y;
#pragma unroll
  for (int p = 0; p < 2; ++p) {
    int c = tid + p * 256;
    int t = c >> 3, dseg = c & 7;
    bf16x8 v = *(const bf16x8*)(in + ((size_t)bh * Tn + t0 + t) * 64 + dseg * 8);
#pragma unroll
    for (int i = 0; i < 8; ++i) L[(dseg * 8 + i) * 72 + t] = v[i];
  }
  __syncthreads();
#pragma unroll
  for (int p = 0; p < 2; ++p) {
    int c = tid + p * 256;
    int d = c >> 3, tseg = c & 7;
    bf16x8 v = *(const bf16x8*)&L[d * 72 + tseg * 8];
    *(bf16x8*)(out + ((size_t)bh * 64 + d) * Tn + t0 + tseg * 8) = v;
  }
}

// ---------------------------------------------------------------------------
// bf16 MFMA GEMM (m97 recipe): 128x128 tile, BK=32, 4 waves (2x2 of 64x64).
// SMODE 0: bf16 C0[m*N+n]
// SMODE 1: per-head q|k split (blockIdx.z=h, N=128)
// SMODE 2: bf16 [B,H,T,D]
// SMODE 3: fp32 C0[m*N+n]
// ---------------------------------------------------------------------------
template <int SMODE, int BIAS>
__global__ __launch_bounds__(256) void gemm_mfma(
    const short* __restrict__ A, const short* __restrict__ Bm,
    const float* __restrict__ bias, void* __restrict__ C0,
    void* __restrict__ C1, int M, int N, int K, int bstride) {
  __shared__ short As[128 * 32];
  __shared__ short Bs[128 * 32];
  const int tid = threadIdx.x;
  const int lane = tid & 63, l16 = lane & 15, quad = lane >> 4;
  const int wave = tid >> 6;
  const int wm = (wave >> 1) * 64, wn = (wave & 1) * 64;
  const int m0 = blockIdx.x * 128, n0 = blockIdx.y * 128;
  const short* Bp = Bm + (size_t)blockIdx.z * bstride;

  f32x4 acc[4][4];
#pragma unroll
  for (int i = 0; i < 4; ++i)
#pragma unroll
    for (int j = 0; j < 4; ++j) acc[i][j] = f32x4{0.f, 0.f, 0.f, 0.f};

  const int arow = tid >> 2, achk = (tid & 3) * 8;
  for (int k0 = 0; k0 < K; k0 += 32) {
#pragma unroll
    for (int p = 0; p < 2; ++p) {
      gld16(A + (size_t)(m0 + p * 64 + arow) * K + k0 + achk,
            As + p * 2048 + tid * 8);
      gld16(Bp + (size_t)(n0 + p * 64 + arow) * K + k0 + achk,
            Bs + p * 2048 + tid * 8);
    }
    __syncthreads();
    bf16x8 af[4], bf[4];
#pragma unroll
    for (int i = 0; i < 4; ++i)
      af[i] = *(const bf16x8*)&As[(wm + i * 16 + l16) * 32 + quad * 8];
#pragma unroll
    for (int j = 0; j < 4; ++j)
      bf[j] = *(const bf16x8*)&Bs[(wn + j * 16 + l16) * 32 + quad * 8];
#pragma unroll
    for (int i = 0; i < 4; ++i)
#pragma unroll
      for (int j = 0; j < 4; ++j)
        acc[i][j] =
            __builtin_amdgcn_mfma_f32_16x16x32_bf16(af[i], bf[j], acc[i][j], 0, 0, 0);
    __syncthreads();
  }

  float bj[4];
#pragma unroll
  for (int j = 0; j < 4; ++j)
    bj[j] = BIAS ? bias[n0 + wn + j * 16 + l16] : 0.f;

#pragma unroll
  for (int i = 0; i < 4; ++i) {
#pragma unroll
    for (int r = 0; r < 4; ++r) {
      int m = m0 + wm + i * 16 + quad * 4 + r;
      int b = m >> 11, t = m & 2047;
#pragma unroll
      for (int j = 0; j < 4; ++j) {
        int n = n0 + wn + j * 16 + l16;
        float val = acc[i][j][r] + bj[j];
        if (SMODE == 0) {
          ((short*)C0)[(size_t)m * N + n] = f2bf(val);
        } else if (SMODE == 1) {
          int bh = b * Hn + (int)blockIdx.z;
          short* dst = (short*)(n < 64 ? C0 : C1);
          dst[((size_t)bh * Tn + t) * 64 + (n & 63)] = f2bf(val);
        } else if (SMODE == 2) {
          int h = n >> 6, d = n & 63;
          ((short*)C0)[(((size_t)(b * Hn + h)) * Tn + t) * 64 + d] = f2bf(val);
        } else {
          ((float*)C0)[(size_t)m * N + n] = val;
        }
      }
    }
  }
}

// ---------------------------------------------------------------------------
// MFMA flash attention v5: key-split for load balance.
// Work items per bh (24 blocks, heavy-first constant order):
//   qt 0..7  : single block, full key range (2qt+2 tiles, <=16)
//   qt 8..15 : two blocks, halves of key range (qt+1 tiles each, <=16)
// Split partials: no-max softmax => partial O (unnormalized) and l are
// ADDITIVE across halves; combine kernel sums and normalizes.
// Block = 4 waves, 128 q-rows (wave: 32 rows = 2 row-groups).
// K/VT staged in LDS via global_load_lds with XOR chunk swizzle.
// ---------------------------------------------------------------------------
__constant__ unsigned char ORD[24] = {28, 62, 63, 58, 59, 24, 54, 55,
                                      50, 51, 20, 46, 47, 42, 43, 16,
                                      38, 39, 34, 35, 12, 8, 4, 0};
#define PP 72
__global__ __launch_bounds__(256) void atn5(
    const short* __restrict__ Qg, const short* __restrict__ Kg,
    const short* __restrict__ VTg, short* __restrict__ Yb,
    short* __restrict__ Opart, float* __restrict__ Lpart) {
  __shared__ short Ks[64 * 64];
  __shared__ short Vt[64 * 64];
  __shared__ short Ps[4 * 16 * PP];

  const int tid = threadIdx.x;
  const int wave = tid >> 6, lane = tid & 63;
  const int l16 = lane & 15, quad = lane >> 4;
  const unsigned v = ORD[blockIdx.x];
  const int qt = v >> 2, split = (v >> 1) & 1, half = v & 1;
  const int bh = blockIdx.y;
  const int wtrow = qt * 128 + wave * 32;
  const size_t kb = (size_t)bh * Tn * 64;
  const size_t vb = (size_t)bh * 64 * Tn;
  const int j0 = split ? half * (qt + 1) : 0;
  const int jn = split ? (qt + 1) : (2 * qt + 2);

  bf16x8 qf[2][2];
#pragma unroll
  for (int rg = 0; rg < 2; ++rg)
#pragma unroll
    for (int s = 0; s < 2; ++s)
      qf[rg][s] = *(const bf16x8*)(Qg + kb +
          (size_t)(wtrow + rg * 16 + l16) * 64 + s * 32 + quad * 8);

  f32x4 o[2][4];
#pragma unroll
  for (int rg = 0; rg < 2; ++rg)
#pragma unroll
    for (int dt = 0; dt < 4; ++dt) o[rg][dt] = f32x4{0.f, 0.f, 0.f, 0.f};
  float lp[2][4] = {{0.f, 0.f, 0.f, 0.f}, {0.f, 0.f, 0.f, 0.f}};

  const int c0r = tid >> 3;
  const int c0slot = tid & 7;
#define STAGE(j)                                                              \
  {                                                                           \
    _Pragma("unroll") for (int p = 0; p < 2; ++p) {                           \
      int row = c0r + p * 32;                                                 \
      int seg = c0slot ^ (row & 7);                                           \
      gld16(Kg + kb + (size_t)((j) * 64 + row) * 64 + seg * 8,                \
            Ks + (tid + p * 256) * 8);                                        \
      gld16(VTg + vb + (size_t)row * Tn + (j) * 64 + seg * 8,                 \
            Vt + (tid + p * 256) * 8);                                        \
    }                                                                         \
  }

  STAGE(j0);
  short* pw = &Ps[wave * 16 * PP];
  const int xs = l16 & 7;

  for (int jj = 0; jj < jn; ++jj) {
    const int j = j0 + jj;
    __syncthreads();
    const bool act1 = (j * 64 <= wtrow + 31);
    const bool act0 = (j * 64 <= wtrow + 15);
    f32x4 sa[2][4];
    bf16x8 vf[4][2];
    if (act1) {
      bf16x8 kf[4][2];
#pragma unroll
      for (int ct = 0; ct < 4; ++ct)
#pragma unroll
        for (int s = 0; s < 2; ++s)
          kf[ct][s] = *(const bf16x8*)&Ks[(ct * 16 + l16) * 64 +
                                          ((s * 4 + quad) ^ xs) * 8];
#pragma unroll
      for (int rg = 0; rg < 2; ++rg) {
        if (rg == 0 && !act0) continue;
#pragma unroll
        for (int ct = 0; ct < 4; ++ct) {
          sa[rg][ct] = f32x4{0.f, 0.f, 0.f, 0.f};
#pragma unroll
          for (int s = 0; s < 2; ++s)
            sa[rg][ct] = __builtin_amdgcn_mfma_f32_16x16x32_bf16(
                qf[rg][s], kf[ct][s], sa[rg][ct], 0, 0, 0);
        }
      }
#pragma unroll
      for (int dt = 0; dt < 4; ++dt)
#pragma unroll
        for (int s = 0; s < 2; ++s)
          vf[dt][s] = *(const bf16x8*)&Vt[(dt * 16 + l16) * 64 +
                                          ((s * 4 + quad) ^ xs) * 8];
    }
    __syncthreads();
    if (jj + 1 < jn) STAGE(j0 + jj + 1);

    if (act1) {
#pragma unroll
      for (int rg = 0; rg < 2; ++rg) {
        if (rg == 0 && !act0) continue;
        const int rbase = wtrow + rg * 16;
        const bool full = (j * 64 + 63 <= rbase);
#pragma unroll
        for (int ct = 0; ct < 4; ++ct) {
          const int u = j * 64 + ct * 16 + l16;
#pragma unroll
          for (int r = 0; r < 4; ++r) {
            float e;
            if (full) {
              e = __expf(sa[rg][ct][r] * SCALE);
            } else {
              const int t = rbase + quad * 4 + r;
              e = (u <= t) ? __expf(sa[rg][ct][r] * SCALE) : 0.f;
            }
            lp[rg][r] += e;
            pw[(quad * 4 + r) * PP + ct * 16 + l16] = f2bf(e);
          }
        }
        bf16x8 pf[2];
#pragma unroll
        for (int s = 0; s < 2; ++s)
          pf[s] = *(const bf16x8*)&pw[l16 * PP + s * 32 + quad * 8];
#pragma unroll
        for (int dt = 0; dt < 4; ++dt)
#pragma unroll
          for (int s = 0; s < 2; ++s)
            o[rg][dt] = __builtin_amdgcn_mfma_f32_16x16x32_bf16(
                pf[s], vf[dt][s], o[rg][dt], 0, 0, 0);
      }
    }
  }

  const int row = lane >> 2, cseg = lane & 3;
  if (!split) {
    // normalize and write yb
    const int b = bh >> 4, h = bh & 15;
#pragma unroll
    for (int rg = 0; rg < 2; ++rg) {
      float inv[4];
#pragma unroll
      for (int r = 0; r < 4; ++r) {
        float l = lp[rg][r];
        l += __shfl_xor(l, 1);
        l += __shfl_xor(l, 2);
        l += __shfl_xor(l, 4);
        l += __shfl_xor(l, 8);
        inv[r] = 1.f / l;
      }
#pragma unroll
      for (int dt = 0; dt < 4; ++dt)
#pragma unroll
        for (int r = 0; r < 4; ++r)
          pw[(quad * 4 + r) * PP + dt * 16 + l16] = f2bf(o[rg][dt][r] * inv[r]);
      bf16x8 y0 = *(const bf16x8*)&pw[row * PP + cseg * 16];
      bf16x8 y1 = *(const bf16x8*)&pw[row * PP + cseg * 16 + 8];
      short* dst = Yb + ((size_t)(b * Tn + wtrow + rg * 16 + row)) * Cn +
                   h * 64 + cseg * 16;
      *(bf16x8*)dst = y0;
      *(bf16x8*)(dst + 8) = y1;
    }
  } else {
    // store unnormalized bf16 O partial + fp32 l partial
    const int slot = ((bh * 8 + (qt - 8)) * 2 + half);
#pragma unroll
    for (int rg = 0; rg < 2; ++rg) {
      float lred[4];
#pragma unroll
      for (int r = 0; r < 4; ++r) {
        float l = lp[rg][r];
        l += __shfl_xor(l, 1);
        l += __shfl_xor(l, 2);
        l += __shfl_xor(l, 4);
        l += __shfl_xor(l, 8);
        lred[r] = l;
      }
#pragma unroll
      for (int dt = 0; dt < 4; ++dt)
#pragma unroll
        for (int r = 0; r < 4; ++r)
          pw[(quad * 4 + r) * PP + dt * 16 + l16] = f2bf(o[rg][dt][r]);
      bf16x8 y0 = *(const bf16x8*)&pw[row * PP + cseg * 16];
      bf16x8 y1 = *(const bf16x8*)&pw[row * PP + cseg * 16 + 8];
      short* dst = Opart + ((size_t)slot * 128 + wave * 32 + rg * 16 + row) * 64 +
                   cseg * 16;
      *(bf16x8*)dst = y0;
      *(bf16x8*)(dst + 8) = y1;
      if (l16 == 0) {
#pragma unroll
        for (int r = 0; r < 4; ++r)
          Lpart[slot * 128 + wave * 32 + rg * 16 + quad * 4 + r] = lred[r];
      }
    }
  }
}

// ---------------------------------------------------------------------------
// combine: for qt 8..15, y = (Oa + Ob) / (la + lb) -> yb bf16
// ---------------------------------------------------------------------------
__global__ __launch_bounds__(256) void combine_k(
    const short* __restrict__ Opart, const float* __restrict__ Lpart,
    short* __restrict__ Yb) {
  int gid = blockIdx.x * 256 + threadIdx.x;  // 524288
  int seg = gid & 7, row = (gid >> 3) & 127, qtr = (gid >> 10) & 7,
      bh = gid >> 13;
  int slotA = (bh * 8 + qtr) * 2, slotB = slotA + 1;
  float la = Lpart[slotA * 128 + row], lb = Lpart[slotB * 128 + row];
  float inv = 1.f / (la + lb);
  bf16x8 a = *(const bf16x8*)(Opart + ((size_t)slotA * 128 + row) * 64 + seg * 8);
  bf16x8 b = *(const bf16x8*)(Opart + ((size_t)slotB * 128 + row) * 64 + seg * 8);
  bf16x8 y;
#pragma unroll
  for (int i = 0; i < 8; ++i) y[i] = f2bf((bf2f(a[i]) + bf2f(b[i])) * inv);
  int t = (qtr + 8) * 128 + row, bb = bh >> 4, h = bh & 15;
  *(bf16x8*)(Yb + ((size_t)(bb * Tn + t)) * Cn + h * 64 + seg * 8) = y;
}

// ---------------------------------------------------------------------------
extern "C" void kernel_launch(void* const* d_in, const int* in_sizes, int n_in,
                              void* d_out, int out_size, void* d_ws,
                              size_t ws_size, hipStream_t stream) {
  const float* x        = (const float*)d_in[0];
  const float* basis_w  = (const float*)d_in[1];
  const float* u_factor = (const float*)d_in[2];
  const float* v_factor = (const float*)d_in[3];
  const float* v_proj_w = (const float*)d_in[4];
  const float* v_proj_b = (const float*)d_in[5];
  const float* o_proj_w = (const float*)d_in[6];
  const float* o_proj_b = (const float*)d_in[7];
  float* out = (float*)d_out;

  char* ws = (char*)d_ws;
  const size_t NX = (size_t)Bn * Tn * Cn;          // 8,388,608
  short* xb      = (short*)ws; ws += NX * 2;       // [8192,1024]  (contig with next 3!)
  short* bwb     = (short*)ws; ws += (size_t)Rn * Cn * 2;        // [256,1024]
  short* vpb     = (short*)ws; ws += (size_t)Cn * Cn * 2;        // [1024,1024]
  short* opb     = (short*)ws; ws += (size_t)Cn * Cn * 2;
  short* uvb     = (short*)ws; ws += (size_t)Hn * 128 * Rn * 2;  // [16,128,256]
  short* latentb = (short*)ws; ws += (size_t)Bn * Tn * Rn * 2;   // [8192,256]
  short* Qb      = (short*)ws; ws += NX * 2;       // [bh,T,64]
  short* Kb      = (short*)ws; ws += NX * 2;
  short* vtmp    = (short*)ws; ws += NX * 2;       // [bh,T,64]
  short* VTb     = (short*)ws; ws += NX * 2;       // [bh,64,T]
  short* yb      = (short*)ws; ws += NX * 2;       // [8192,1024]
  short* Opart   = (short*)ws; ws += (size_t)1024 * 128 * 64 * 2;  // 33.5 MB
  float* Lpart   = (float*)ws;                     // 1024*128 f32

  dim3 blk(256);
  cvtall<<<dim3(5504), blk, 0, stream>>>(x, basis_w, v_proj_w, o_proj_w,
                                         u_factor, v_factor, xb, uvb);

  // latent = x @ basis^T : bf16 [8192,256]
  gemm_mfma<0, 0><<<dim3(64, 2, 1), blk, 0, stream>>>(
      xb, bwb, nullptr, latentb, nullptr, 8192, 256, 1024, 0);
  // q|k = latent @ uv[h]^T : per-head split into Qb, Kb
  gemm_mfma<1, 0><<<dim3(64, 1, 16), blk, 0, stream>>>(
      latentb, uvb, nullptr, Qb, Kb, 8192, 128, 256, 128 * 256);
  // v = x @ v_proj^T + b -> [bh,T,64]
  gemm_mfma<2, 1><<<dim3(64, 8, 1), blk, 0, stream>>>(
      xb, vpb, v_proj_b, vtmp, nullptr, 8192, 1024, 1024, 0);
  // V^T [bh,64,T]
  vtrans_k<<<dim3(32, 64), blk, 0, stream>>>(vtmp, VTb);
  // attention (split-key) -> yb (qt<8) + partials (qt>=8)
  atn5<<<dim3(24, 64), blk, 0, stream>>>(Qb, Kb, VTb, yb, Opart, Lpart);
  combine_k<<<dim3(2048), blk, 0, stream>>>(Opart, Lpart, yb);
  // out = yb @ o_proj^T + b : fp32
  gemm_mfma<3, 1><<<dim3(64, 8, 1), blk, 0, stream>>>(
      yb, opb, o_proj_b, out, nullptr, 8192, 1024, 1024, 0);
}